// Round 4
// baseline (714.473 us; speedup 1.0000x reference)
//
#include <hip/hip_runtime.h>

#define NX 24
#define NU 8
#define TH 100
#define NB 512
#define REGF 1e-6f

// ---------------- LDS layout (float offsets) ----------------
#define OFF_ECOLT 0          // [32][36]  EcolT[r][k] = F[k][r], F=[A|B] 24x32
#define OFF_V     1152       // [24][36]
#define OFF_W2T   2016       // [32][36]  W2T[jc][k] = (V*F)[k][jc]
#define OFF_Q2    3168       // [32][33]  Q2[r][jc] = full Q matrix
#define OFF_KSM   4224       // [8][33]   K rows
#define OFF_KV    4488       // [8]
#define OFF_QSM   4496       // [32]      q_t
#define OFF_QVEC  4528       // [32]      [Qx | Qu]
#define OFF_VSM   4560       // [32] (24 used)  v vector
#define OFF_TILES 4592       // [2][1024] C_t tiles (double buffer)
#define OFF_CALL  6640       // [3200]
#define OFF_XRALL 9840       // [2424]
#define OFF_URALL 12264      // [800]
#define SMEM_FLOATS 13064    // 52.3 KB
// forward-phase aliases (regions dead by then)
#define OFF_KF    OFF_TILES      // 2 x 256
#define OFF_XFB   OFF_W2T        // 2 x 28
#define OFF_UF    (OFF_W2T + 56) // 8
#define OFF_OUTB  OFF_CALL       // 3224 (spills 24 into dead XRALL region: ok)

// inter-phase barrier: LDS-only ordering (no vmem dependency between phases)
#define BARRIER() asm volatile("s_waitcnt lgkmcnt(0)\n\ts_barrier" ::: "memory")
// top-of-step: wait own vmem (tile staged last step) + LDS, then align waves.
// vmcnt(0) is count-free: correct regardless of compiler-inserted vmem ops.
#define STEP_SYNC() asm volatile("s_waitcnt vmcnt(0) lgkmcnt(0)\n\ts_barrier" ::: "memory")

// tile stored with per-row XOR swizzle on 16B quads: quad j4 of row r at slot (j4 ^ (r&7))
#define TILE_ELEM(tb, r, j) sm[(tb) + (r)*32 + ((((j) >> 2) ^ ((r) & 7)) << 2) + ((j) & 3)]

__device__ __forceinline__ void stage_tile(const float* Cg, int b, int t,
                                           float* lds_base, int tid) {
  // linear LDS dest (wave base + lane*16B); source pre-swizzled (T2/m173, rule #21)
  const int r = tid >> 3, j4s = tid & 7;
  const int j4 = j4s ^ (r & 7);
  const float* src = Cg + ((size_t)b * TH + t) * 1024 + r * 32 + j4 * 4;
  __builtin_amdgcn_global_load_lds((const __attribute__((address_space(1))) void*)src,
                                   (__attribute__((address_space(3))) void*)(lds_base + tid * 4),
                                   16, 0, 0);
}

__device__ __forceinline__ void stage_K(const float* wsb, int slot, float* dst, int lane,
                                        unsigned idx0, unsigned wscap) {
#pragma unroll
  for (int r = 0; r < 4; ++r) {
    if (r * 64 + lane < 200 && idx0 + (unsigned)slot * 200u + r * 64 + lane < wscap) {
      __builtin_amdgcn_global_load_lds(
          (const __attribute__((address_space(1))) void*)(wsb + (size_t)slot * 200 + r * 64 + lane),
          (__attribute__((address_space(3))) void*)(dst + r * 64),
          4, 0, 0);
    }
  }
}

extern "C" __global__ void __launch_bounds__(256, 2)
lqr_kernel(const float* __restrict__ x0g, const float* __restrict__ Cg,
           const float* __restrict__ cg,  const float* __restrict__ Cfg,
           const float* __restrict__ cfg, const float* __restrict__ xrg,
           const float* __restrict__ urg, const float* __restrict__ Adg,
           const float* __restrict__ Bdg, float* __restrict__ outg,
           float* __restrict__ ws, unsigned wstride, unsigned wscap) {
  __shared__ __align__(16) float sm[SMEM_FLOATS];
  const int tid = threadIdx.x;
  const int b   = blockIdx.x;
  const int jc  = tid & 31;   // owned column 0..31
  const int hw  = tid >> 5;   // half-wave group 0..7

  const unsigned wbase = (unsigned)b * wstride;   // wstride==0 -> safe aliased fallback
  float* wsb = ws + wbase;

  // ---------------- init: bulk loads ----------------
  for (int idx = tid; idx < 768; idx += 256) {       // EcolT[r][k] = F[k][r]
    int k = idx >> 5, r = idx & 31;
    float v = (r < NX) ? Adg[k * NX + r] : Bdg[k * NU + (r - NX)];
    sm[OFF_ECOLT + r * 36 + k] = v;
  }
  for (int idx = tid; idx < 576; idx += 256) {       // V = C_final[:24,:24]
    int i = idx / 24, j = idx % 24;
    sm[OFF_V + i * 36 + j] = Cfg[(size_t)b * 1024 + i * 32 + j];
  }
  for (int idx = tid; idx < 3200; idx += 256) sm[OFF_CALL  + idx] = cg[(size_t)b * 3200 + idx];
  for (int idx = tid; idx < 2424; idx += 256) sm[OFF_XRALL + idx] = xrg[(size_t)b * 2424 + idx];
  for (int idx = tid; idx < 800;  idx += 256) sm[OFF_URALL + idx] = urg[(size_t)b * 800 + idx];
  if (tid < 8) {                                      // zero-init KSM/KV (step-0 store reads them)
    sm[OFF_KV + tid] = 0.f;
#pragma unroll
    for (int j = 0; j < 33; ++j) sm[OFF_KSM + tid * 33 + j] = 0.f;
  }
  __syncthreads();

  // per-lane F column registers (loop invariant): Er[m] = F[m][jc]
  float Er[24];
#pragma unroll
  for (int k4 = 0; k4 < 6; ++k4) {
    float4 e = *reinterpret_cast<const float4*>(&sm[OFF_ECOLT + jc * 36 + k4 * 4]);
    Er[k4 * 4 + 0] = e.x; Er[k4 * 4 + 1] = e.y; Er[k4 * 4 + 2] = e.z; Er[k4 * 4 + 3] = e.w;
  }

  // v_T = c_final[:24] - V @ x_ref[:,100]
  if (tid < 24) {
    float s = cfg[(size_t)b * 32 + tid];
#pragma unroll
    for (int j = 0; j < 24; ++j) s -= sm[OFF_V + tid * 36 + j] * sm[OFF_XRALL + 100 * 24 + j];
    sm[OFF_VSM + tid] = s;
  }

  // prologue: stage tile for k=0 (t=99) into buffer 0
  stage_tile(Cg, b, 99, &sm[OFF_TILES + 0], tid);
  __syncthreads();   // full drain: tile 0 ready, init LDS visible

  // ---------------- backward Riccati loop ----------------
  for (int k = 0; k < TH; ++k) {
    const int t = 99 - k;

    // top-of-step: tile k (staged one step ago) ready; waves aligned
    STEP_SYNC();

    // issue next tile (k+1) into the other buffer; drained at next STEP_SYNC.
    // Full iter-k compute (~1500 cy) hides the HBM latency.
    {
      int tp = (t >= 1) ? (t - 1) : 0;   // k=99: dummy re-stage of t=0 (never read)
      stage_tile(Cg, b, tp, &sm[OFF_TILES + ((k + 1) & 1) * 1024], tid);
    }
    // store previous step's K/kv (k=0 stores zeros to unused slot 100)
    if (tid < 200 && wbase + (unsigned)(100 - k) * 200u + tid < wscap) {
      float v = (tid < 192) ? sm[OFF_KSM + (tid / 24) * 33 + (tid % 24)]
                            : sm[OFF_KV + (tid - 192)];
      wsb[(size_t)(100 - k) * 200 + tid] = v;
    }

    const int tb = OFF_TILES + (k & 1) * 1024;

    // ---- phase 1: W2T[jc][i] = dot(V row i, F col jc); q rows (4 lanes/half-wave) ----
    {
      const int i0 = 3 * hw;
      float a0 = 0.f, a1 = 0.f, a2 = 0.f;
#pragma unroll
      for (int m4 = 0; m4 < 6; ++m4) {
        float4 v0 = *reinterpret_cast<const float4*>(&sm[OFF_V + (i0 + 0) * 36 + m4 * 4]);
        float4 v1 = *reinterpret_cast<const float4*>(&sm[OFF_V + (i0 + 1) * 36 + m4 * 4]);
        float4 v2 = *reinterpret_cast<const float4*>(&sm[OFF_V + (i0 + 2) * 36 + m4 * 4]);
        a0 += v0.x * Er[m4*4] + v0.y * Er[m4*4+1] + v0.z * Er[m4*4+2] + v0.w * Er[m4*4+3];
        a1 += v1.x * Er[m4*4] + v1.y * Er[m4*4+1] + v1.z * Er[m4*4+2] + v1.w * Er[m4*4+3];
        a2 += v2.x * Er[m4*4] + v2.y * Er[m4*4+1] + v2.z * Er[m4*4+2] + v2.w * Er[m4*4+3];
      }
      sm[OFF_W2T + jc * 36 + i0 + 0] = a0;
      sm[OFF_W2T + jc * 36 + i0 + 1] = a1;
      sm[OFF_W2T + jc * 36 + i0 + 2] = a2;
      // q[r] = c[r] - C_t[r,:] . [xr;ur],  row r == jc, 4 rows per half-wave
      if ((jc >> 2) == hw) {
        float s = sm[OFF_CALL + t * 32 + jc];
#pragma unroll
        for (int j = 0; j < 24; ++j) s -= TILE_ELEM(tb, jc, j) * sm[OFF_XRALL + t * 24 + j];
#pragma unroll
        for (int j = 0; j < 8; ++j)  s -= TILE_ELEM(tb, jc, 24 + j) * sm[OFF_URALL + t * 8 + j];
        sm[OFF_QSM + jc] = s;
      }
    }
    BARRIER();

    // ---- phase 2: Q2[r][jc] = C_t[r][jc] + sum_k F[k][r]*W2[k][jc] (+reg) ; Qvec ----
    {
      float4 w[6];
#pragma unroll
      for (int k4 = 0; k4 < 6; ++k4)
        w[k4] = *reinterpret_cast<const float4*>(&sm[OFF_W2T + jc * 36 + k4 * 4]);
      const int r0 = 4 * hw;
#pragma unroll
      for (int rr = 0; rr < 4; ++rr) {
        const int r = r0 + rr;
        float acc = TILE_ELEM(tb, r, jc);
#pragma unroll
        for (int k4 = 0; k4 < 6; ++k4) {
          float4 e = *reinterpret_cast<const float4*>(&sm[OFF_ECOLT + r * 36 + k4 * 4]);
          acc += e.x * w[k4].x + e.y * w[k4].y + e.z * w[k4].z + e.w * w[k4].w;
        }
        if (r >= 24 && r == jc) acc += REGF;
        sm[OFF_Q2 + r * 33 + jc] = acc;
      }
      if (hw == 0) {  // Qvec[jc] = q[jc] + sum_k v[k]*F[k][jc]
        float s = sm[OFF_QSM + jc];
#pragma unroll
        for (int k4 = 0; k4 < 6; ++k4) {
          float4 v4 = *reinterpret_cast<const float4*>(&sm[OFF_VSM + k4 * 4]);
          s += v4.x * Er[k4*4] + v4.y * Er[k4*4+1] + v4.z * Er[k4*4+2] + v4.w * Er[k4*4+3];
        }
        sm[OFF_QVEC + jc] = s;
      }
    }
    BARRIER();

    // ---- phase 3: 25 lanes solve Quu X = -[Qux | Qu] via redundant 8x8 Cholesky ----
    if (tid < 25) {
      float Lf[36], invd[8], r8[8];
#define LL(i, j) Lf[((i) * ((i) + 1)) / 2 + (j)]
#pragma unroll
      for (int i = 0; i < 8; ++i)
#pragma unroll
        for (int j = 0; j < 8; ++j)
          if (j <= i) LL(i, j) = sm[OFF_Q2 + (24 + i) * 33 + (24 + j)];
#pragma unroll
      for (int j = 0; j < 8; ++j) {
        float s = LL(j, j);
#pragma unroll
        for (int kk = 0; kk < 8; ++kk) if (kk < j) s -= LL(j, kk) * LL(j, kk);
        float d = sqrtf(s);
        invd[j] = __builtin_amdgcn_rcpf(d);
#pragma unroll
        for (int i2 = 0; i2 < 8; ++i2) if (i2 > j) {
          float s2 = LL(i2, j);
#pragma unroll
          for (int kk = 0; kk < 8; ++kk) if (kk < j) s2 -= LL(i2, kk) * LL(j, kk);
          LL(i2, j) = s2 * invd[j];
        }
      }
#pragma unroll
      for (int i = 0; i < 8; ++i)
        r8[i] = -((tid < 24) ? sm[OFF_Q2 + (24 + i) * 33 + tid] : sm[OFF_QVEC + 24 + i]);
#pragma unroll
      for (int i = 0; i < 8; ++i) {          // L y = r
        float s = r8[i];
#pragma unroll
        for (int j = 0; j < 8; ++j) if (j < i) s -= LL(i, j) * r8[j];
        r8[i] = s * invd[i];
      }
#pragma unroll
      for (int i = 7; i >= 0; --i) {         // L^T x = y
        float s = r8[i];
#pragma unroll
        for (int j = 0; j < 8; ++j) if (j > i) s -= LL(j, i) * r8[j];
        r8[i] = s * invd[i];
      }
      if (tid < 24) {
#pragma unroll
        for (int i = 0; i < 8; ++i) sm[OFF_KSM + i * 33 + tid] = r8[i];
      } else {
#pragma unroll
        for (int i = 0; i < 8; ++i) sm[OFF_KV + i] = r8[i];
      }
#undef LL
    }
    BARRIER();

    // ---- phase 4: V <- sym(Qxx + Qux^T K) ; v <- Qx + Qux^T kv ----
    if (jc < 24) {
      float kcol[8], qxc[8];
#pragma unroll
      for (int kk = 0; kk < 8; ++kk) {
        kcol[kk] = sm[OFF_KSM + kk * 33 + jc];
        qxc[kk]  = sm[OFF_Q2 + (24 + kk) * 33 + jc];
      }
      const int i0 = 3 * hw;
#pragma unroll
      for (int rr = 0; rr < 3; ++rr) {
        const int i = i0 + rr;
        float s = 0.5f * (sm[OFF_Q2 + i * 33 + jc] + sm[OFF_Q2 + jc * 33 + i]);
        float d = 0.f;
#pragma unroll
        for (int kk = 0; kk < 8; ++kk) {
          d += sm[OFF_Q2 + (24 + kk) * 33 + i] * kcol[kk];
          d += sm[OFF_KSM + kk * 33 + i] * qxc[kk];
        }
        sm[OFF_V + i * 36 + jc] = s + 0.5f * d;
      }
    } else if (jc < 27) {
      const int i = 3 * hw + (jc - 24);
      float s = sm[OFF_QVEC + i];
#pragma unroll
      for (int kk = 0; kk < 8; ++kk) s += sm[OFF_Q2 + (24 + kk) * 33 + i] * sm[OFF_KV + kk];
      sm[OFF_VSM + i] = s;
    }
    // next iteration's STEP_SYNC provides the phase4 -> phase1 sync
  }

  // final K (t=0) -> slot 0
  STEP_SYNC();
  if (tid < 200 && wbase + (unsigned)tid < wscap) {
    float v = (tid < 192) ? sm[OFF_KSM + (tid / 24) * 33 + (tid % 24)]
                          : sm[OFF_KV + (tid - 192)];
    wsb[tid] = v;
  }
  __syncthreads();  // full drain (vmcnt+lgkm): all K slots visible in ws

  // ---------------- forward rollout: wave 0 only ----------------
  if (tid < 64) {
    const int lane = tid;
    if (lane < 24) {
      float xv = x0g[(size_t)b * 24 + lane];
      sm[OFF_XFB + lane] = xv;       // x buffer 0
      sm[OFF_OUTB + lane] = xv;      // X[b,0]
    }
    stage_K(wsb, 0, &sm[OFF_KF + 0], lane, wbase, wscap);
    for (int s = 0; s < TH; ++s) {
      // slot s ready (staged last iter, one step of compute to cover latency)
      asm volatile("s_waitcnt vmcnt(0) lgkmcnt(0)" ::: "memory");
      int sp = (s + 1 <= 99) ? (s + 1) : 99;   // s=99: dummy, never read
      stage_K(wsb, sp, &sm[OFF_KF + ((s + 1) & 1) * 256], lane, wbase, wscap);
      const int kb = OFF_KF + (s & 1) * 256;
      const int xb = OFF_XFB + (s & 1) * 28;
      if (lane < 8) {
        float u = sm[kb + 192 + lane];
#pragma unroll
        for (int j = 0; j < 24; ++j) u += sm[kb + lane * 24 + j] * sm[xb + j];
        sm[OFF_UF + lane] = u;
        sm[OFF_OUTB + 2424 + s * 8 + lane] = u;
      }
      asm volatile("s_waitcnt lgkmcnt(0)" ::: "memory");
      if (lane < 24) {
        float xn = 0.f;
#pragma unroll
        for (int j = 0; j < 24; ++j) xn += sm[OFF_ECOLT + j * 36 + lane] * sm[xb + j];            // A[lane][j]
#pragma unroll
        for (int j = 0; j < 8; ++j)  xn += sm[OFF_ECOLT + (24 + j) * 36 + lane] * sm[OFF_UF + j]; // B[lane][j]
        sm[OFF_XFB + ((s + 1) & 1) * 28 + lane] = xn;
        sm[OFF_OUTB + (s + 1) * 24 + lane] = xn;
      }
      asm volatile("s_waitcnt lgkmcnt(0)" ::: "memory");
    }
  }
  __syncthreads();
  for (int e = tid; e < 3224; e += 256) outg[(size_t)b * 3224 + e] = sm[OFF_OUTB + e];
}

extern "C" void kernel_launch(void* const* d_in, const int* in_sizes, int n_in,
                              void* d_out, int out_size, void* d_ws, size_t ws_size,
                              hipStream_t stream) {
  (void)in_sizes; (void)n_in; (void)out_size;
  const float* x0 = (const float*)d_in[0];
  const float* C  = (const float*)d_in[1];
  const float* c  = (const float*)d_in[2];
  const float* Cf = (const float*)d_in[3];
  const float* cf = (const float*)d_in[4];
  const float* xr = (const float*)d_in[5];
  const float* ur = (const float*)d_in[6];
  const float* Ad = (const float*)d_in[7];
  const float* Bd = (const float*)d_in[8];
  // ws safety: full layout needs 512*101*200 floats (41.4 MB). If d_ws is
  // smaller, alias all blocks to the base region (wrong results but NO OOB
  // access -> clean absmax failure + counters instead of a dead container).
  const size_t need = (size_t)NB * 101 * 200 * sizeof(float);
  unsigned wstride = (ws_size >= need) ? 101u * 200u : 0u;
  unsigned wscap   = (unsigned)(ws_size / sizeof(float));
  lqr_kernel<<<dim3(NB), dim3(256), 0, stream>>>(x0, C, c, Cf, cf, xr, ur, Ad, Bd,
                                                 (float*)d_out, (float*)d_ws,
                                                 wstride, wscap);
}